// Round 9
// baseline (979.229 us; speedup 1.0000x reference)
//
#include <hip/hip_runtime.h>
#include <cstddef>
#include <cstdint>

#define S3 32768  // 32*32*32 spatial positions

typedef short bf16x8 __attribute__((ext_vector_type(8)));   // 8 bf16 in 4 VGPRs
typedef float f32x16 __attribute__((ext_vector_type(16)));

static __device__ inline unsigned short f2bf(float f) {
    unsigned int u = __float_as_uint(f);
    unsigned int r = (u + 0x7FFFu + ((u >> 16) & 1u)) >> 16;  // RNE
    return (unsigned short)r;
}

// unpack 8 bf16 (one uint4) -> 8 fp32
static __device__ inline void bf8_to_f32(uint4 v, float* o) {
    unsigned a[4] = {v.x, v.y, v.z, v.w};
#pragma unroll
    for (int w = 0; w < 4; ++w) {
        o[2 * w]     = __uint_as_float((a[w] & 0xFFFFu) << 16);
        o[2 * w + 1] = __uint_as_float(a[w] & 0xFFFF0000u);
    }
}

// --------- weight transpose: wT[tap][icb][c][kb][chunk(=half*32+ln)][8ic] --
template <int IC, int OC>
__global__ __launch_bounds__(256) void wt_transpose(
    const float* __restrict__ w, unsigned short* __restrict__ wT)
{
    int t = blockIdx.x * 256 + threadIdx.x;  // < 125*IC*OC
    int e = t & 7;
    int chunk = (t >> 3) & 63;
    int kb = (t >> 9) & 1;
    int rest = t >> 10;                       // (tap*ICB + icb)*WOC + c
    int c = rest % (OC / 32); rest /= (OC / 32);
    int icb = rest % (IC / 32);
    int tap = rest / (IC / 32);
    int ln = chunk & 31, half = chunk >> 5;
    int oc = c * 32 + ln;
    int ic = icb * 32 + kb * 16 + half * 8 + e;
    wT[t] = f2bf(w[((size_t)oc * IC + ic) * 125 + tap]);
}

// ---------------- x transpose: xb[b][z][y][x][128 ic] bf16 -----------------
__global__ __launch_bounds__(256) void xb_transpose(
    const float* __restrict__ x, unsigned short* __restrict__ xb)
{
    __shared__ float tile[32][133];
    int zy = blockIdx.x, b = blockIdx.y;
    int t = threadIdx.x, xi = t & 31, ich = t >> 5;
#pragma unroll
    for (int k = 0; k < 16; ++k) {
        int ic = k * 8 + ich;
        tile[xi][ic] = x[(size_t)(b * 128 + ic) * S3 + zy * 32 + xi];
    }
    __syncthreads();
#pragma unroll
    for (int k = 0; k < 2; ++k) {
        int u = t + 256 * k;
        int xx = u >> 4, j = u & 15;
        __align__(16) unsigned short tmp[8];
#pragma unroll
        for (int e = 0; e < 8; ++e) tmp[e] = f2bf(tile[xx][j * 8 + e]);
        *(uint4*)(xb + ((size_t)b * S3 + zy * 32 + xx) * 128 + j * 8) =
            *(const uint4*)tmp;
    }
}

// ---------------- token = mixer_w @ basis ; q = wq[4] @ token --------------
__global__ __launch_bounds__(256) void token_q_kernel(
    const float* __restrict__ basis, const float* __restrict__ mixer,
    const float* __restrict__ wq, float* __restrict__ token,
    float* __restrict__ qbuf)
{
    int s = blockIdx.x * 256 + threadIdx.x;
    float tok[32];
#pragma unroll
    for (int c = 0; c < 32; ++c) tok[c] = 0.f;
#pragma unroll
    for (int r = 0; r < 8; ++r) {
        float bv = basis[r * S3 + s];
#pragma unroll
        for (int c = 0; c < 32; ++c) tok[c] += mixer[c * 8 + r] * bv;
    }
#pragma unroll
    for (int c = 0; c < 32; ++c) token[c * S3 + s] = tok[c];
    const float* wq4 = wq + 4 * 1024;
#pragma unroll
    for (int o = 0; o < 32; ++o) {
        float a = 0.f;
#pragma unroll
        for (int c = 0; c < 32; ++c) a += wq4[o * 32 + c] * tok[c];
        qbuf[o * S3 + s] = a;
    }
}

// -------- attention (row 4 only), two-pass, 4-WAY O-SPLIT (NEW) ------------
// The old layout (1 thread = 1 position x 32 oc) caps the grid at 131072
// threads = 8 waves/CU: occupancy-starved, ~18% VALUBusy (r6 counters), est
// ~200 µs. Split: 4 consecutive lanes share one position, each owns 8 oc.
// QK^T partial dots combined with two __shfl_xor (lane groups are
// wave-internal). VALU/thread 11K -> 2.7K fma; grid 512 -> 2048 blocks
// (~3-4x occupancy). The 4 duplicate xv loads/position hit the same 64B
// line (one transaction per wave group). K/V from xb bf16 (contiguous 64B).
__global__ __launch_bounds__(256) void attention_kernel(
    const unsigned short* __restrict__ xb, const float* __restrict__ token,
    const float* __restrict__ qbuf, const float* __restrict__ wk,
    const float* __restrict__ wv, const float* __restrict__ alpha_p,
    float* __restrict__ out)
{
    int t = blockIdx.x * 256 + threadIdx.x;   // 2048*256 = 4*B*S3 threads
    int g = t >> 2;                           // position index: b*S3 + s
    int os = (t & 3) * 8;                     // this thread's oc range
    int s = g & (S3 - 1);
    int b = g >> 15;

    float q[8];
#pragma unroll
    for (int i = 0; i < 8; ++i) q[i] = qbuf[(size_t)(os + i) * S3 + s];

    const unsigned short* xrow = xb + ((size_t)b * S3 + s) * 128;

    const float scale = 0.17677669529663687f;
    float l[5];
#pragma unroll
    for (int j = 0; j < 5; ++j) {
        float xv[32];
        if (j < 4) {
#pragma unroll
            for (int k = 0; k < 4; ++k)
                bf8_to_f32(*(const uint4*)(xrow + j * 32 + k * 8), xv + k * 8);
        } else {
#pragma unroll
            for (int c = 0; c < 32; ++c) xv[c] = token[(size_t)c * S3 + s];
        }
        const float* wkj = wk + j * 1024 + os * 32;
        float acc = 0.f;
#pragma unroll
        for (int i = 0; i < 8; ++i) {
            float kv = 0.f;
#pragma unroll
            for (int c = 0; c < 32; ++c) kv += wkj[i * 32 + c] * xv[c];
            acc += q[i] * kv;
        }
        // combine the 4 o-partials (lanes 4t..4t+3 share a position)
        acc += __shfl_xor(acc, 1);
        acc += __shfl_xor(acc, 2);
        l[j] = acc * scale;
    }
    float m = l[0];
#pragma unroll
    for (int j = 1; j < 5; ++j) m = fmaxf(m, l[j]);
    float p[5], sum = 0.f;
#pragma unroll
    for (int j = 0; j < 5; ++j) { p[j] = __expf(l[j] - m); sum += p[j]; }
    float inv = alpha_p[0] / sum;

    float ov[8];
#pragma unroll
    for (int i = 0; i < 8; ++i) ov[i] = 0.f;
#pragma unroll
    for (int j = 0; j < 5; ++j) {
        float xv[32];
        if (j < 4) {
#pragma unroll
            for (int k = 0; k < 4; ++k)
                bf8_to_f32(*(const uint4*)(xrow + j * 32 + k * 8), xv + k * 8);
        } else {
#pragma unroll
            for (int c = 0; c < 32; ++c) xv[c] = token[(size_t)c * S3 + s];
        }
        const float* wvj = wv + j * 1024 + os * 32;
        float pj = p[j];
#pragma unroll
        for (int i = 0; i < 8; ++i) {
            float vv = 0.f;
#pragma unroll
            for (int c = 0; c < 32; ++c) vv += wvj[i * 32 + c] * xv[c];
            ov[i] += pj * vv;
        }
    }
#pragma unroll
    for (int i = 0; i < 8; ++i)
        out[((size_t)b * 32 + os + i) * S3 + s] = ov[i] * inv;
}

// ============ conv1: round-1 exact kernel (222.1 µs r1, 223.0 µs r7) =======
// 512-thread block (8 waves), 1 block/CU, block tile OC x (16y x 32x) x 1z.
// 2 oc-halves x 4 y-waves, JT=4. LDS input double-buffer, stage overlapped
// at gp==2, one raw lgkmcnt(0)+s_barrier per window. kb-split conv1
// ABANDONED (r4: spill; r8: diet still spilled + broke latency hiding).
template <int IC, int OC, bool WRITE_H>
__global__ __launch_bounds__(512, 2) void conv_mfma(
    const unsigned short* __restrict__ xin, const uint4* __restrict__ wTq,
    const float* __restrict__ bias, unsigned short* __restrict__ hout,
    float* __restrict__ fout)
{
    constexpr int ICB = IC / 32, WOC = OC / 32;
    constexpr int JT = 2 * WOC;        // 4 conv1
    constexpr int NW = ICB * 5;
    constexpr int NIN = 2880;          // 20 rows * 36 x * 4 chunks
    constexpr int BUF = 20 * 36 * 80;  // 57600 B per buffer
    __shared__ __align__(16) char lds_in[2 * BUF];  // 115.2 KB

    const int tid = threadIdx.x;
    const int wave = tid >> 6, lane = tid & 63;
    const int ln = lane & 31, half = lane >> 5;
    const int ochalf = (WOC == 2) ? (wave >> 2) : 0;
    const int wy = (WOC == 2) ? (wave & 3) : wave;
    const int z = blockIdx.x, ybl = blockIdx.y, b = blockIdx.z;
    const int y0 = ybl * 16;

    const uint4* wTl = wTq + half * 32 + ln;  // lane-fixed chunk offset

    // ---- window-invariant staging geometry (hoisted) ----
    int  goff[6];   // global offset sans (gz, icb) term
    int  loff[6];   // LDS byte offset within a buffer
    bool act[6], yxok[6];
#pragma unroll
    for (int k = 0; k < 6; ++k) {
        int i = tid + 512 * k;
        act[k] = i < NIN;
        int sub = i & 3, cc = i >> 2;
        int x36 = cc % 36, row = cc / 36;
        int gy = y0 - 2 + row, gx = x36 - 2;
        yxok[k] = ((unsigned)gy < 32u) & ((unsigned)gx < 32u);
        goff[k] = (b * 32768 + gy * 32 + gx) * IC + sub * 8;
        loff[k] = row * 2880 + x36 * 80 + sub * 16;
    }

    f32x16 acc[JT];
#pragma unroll
    for (int j = 0; j < JT; ++j)
#pragma unroll
        for (int e = 0; e < 16; ++e) acc[j][e] = 0.f;

    uint4 prei[6];

    auto issue = [&](int icb, int dz) {
        int gz = z + dz - 2;
        bool zok = (unsigned)gz < 32u;
        int zoff = gz * (1024 * IC) + icb * 32;
#pragma unroll
        for (int k = 0; k < 6; ++k) {
            if (act[k]) {
                uint4 v = {0u, 0u, 0u, 0u};
                if (zok & yxok[k])
                    v = *(const uint4*)(xin + goff[k] + zoff);
                prei[k] = v;
            }
        }
    };

    auto stage = [&](int buf) {
        char* base = lds_in + buf * BUF;
#pragma unroll
        for (int k = 0; k < 6; ++k)
            if (act[k]) *(uint4*)(base + loff[k]) = prei[k];
    };

    bf16x8 bufA[5], bufB[5];

    auto fillA = [&](bool valid, int icb, int dz, int dx, int kb,
                     bf16x8 (&buf)[5]) {
        if (!valid) return;
#pragma unroll
        for (int dy = 0; dy < 5; ++dy) {
            int tap = (dz * 5 + dy) * 5 + dx;
            int f = ((tap * ICB + icb) * WOC + ochalf) * 2 + kb;
            buf[dy] = *(const bf16x8*)(wTl + (size_t)f * 64);
        }
    };

    auto compute = [&](const char* base, bf16x8 (&cur)[5], int dx, int kb) {
        bf16x8 brow[JT + 4];
#pragma unroll
        for (int r = 0; r < JT + 4; ++r)
            brow[r] = *(const bf16x8*)(base + (JT * wy + r) * 2880 +
                                       (ln + dx) * 80 + kb * 32 + half * 16);
#pragma unroll
        for (int dy = 0; dy < 5; ++dy)
#pragma unroll
            for (int j = 0; j < JT; ++j)
                acc[j] = __builtin_amdgcn_mfma_f32_32x32x16_bf16(
                    cur[dy], brow[dy + j], acc[j], 0, 0, 0);
    };

    // prologue: fill buf0, prefetch first A fragments
    issue(0, 0);
    fillA(true, 0, 0, 0, 0, bufA);
    stage(0);
    __syncthreads();

    int cur = 0;
    for (int w = 0; w < NW; ++w) {
        int icb = w / 5, dz = w - icb * 5;
        int nw = w + 1;
        int nicb = nw / 5, ndz = nw - nicb * 5;
        bool more = nw < NW;
        const char* rb = lds_in + cur * BUF;

#pragma unroll
        for (int gp = 0; gp < 5; ++gp) {
            fillA(true, icb, dz, gp, 1, bufB);
            compute(rb, bufA, gp, 0);
            if (gp < 4) fillA(true, icb, dz, gp + 1, 0, bufA);
            else        fillA(more, nicb, ndz, 0, 0, bufA);
            if (gp == 0 && more) issue(nicb, ndz);          // next-window loads
            if (gp == 2 && more) stage(cur ^ 1);            // overlapped write
            compute(rb, bufB, gp, 1);
        }
        // one barrier/window: drain only LDS ops; global loads stay in flight
        asm volatile("s_waitcnt lgkmcnt(0)\n\ts_barrier" ::: "memory");
        cur ^= 1;
    }

    __syncthreads();
    if (WRITE_H) {
        // bias + exact GELU, transpose to [x][oc] via LDS scratch (4 y-waves
        // x 32 x x 64 oc rows), store h[b][z][y][x][64] bf16.
#pragma unroll
        for (int j = 0; j < JT; ++j) {
            char* scr = lds_in + wy * (32 * 144);
#pragma unroll
            for (int r = 0; r < 16; ++r) {
                int ocr = (r & 3) + 8 * (r >> 2) + 4 * half;
                int oc = ochalf * 32 + ocr;
                float v = acc[j][r] + bias[oc];
                v = 0.5f * v * (1.f + erff(v * 0.70710678118654752f));
                *(unsigned short*)(scr + ln * 144 + oc * 2) = f2bf(v);
            }
            __syncthreads();
#pragma unroll
            for (int k = 0; k < 2; ++k) {
                int u = tid + 512 * k;          // 1024 = 4 wy * 32 x * 8 un
                int wyi = u >> 8, rem = u & 255;
                int xx = rem >> 3, un = rem & 7;
                uint4 v = *(const uint4*)(lds_in + wyi * (32 * 144) +
                                          xx * 144 + un * 16);
                int y = y0 + 4 * wyi + j;
                *(uint4*)(hout + ((((size_t)b * 32 + z) * 32 + y) * 32 + xx)
                          * 64 + un * 8) = v;
            }
            __syncthreads();
        }
    } else {
        // final: bias + attention (already alpha-scaled in fout) added
#pragma unroll
        for (int j = 0; j < JT; ++j) {
            int y = y0 + JT * wy + j;
#pragma unroll
            for (int r = 0; r < 16; ++r) {
                int oc = (r & 3) + 8 * (r >> 2) + 4 * half;
                size_t o = ((size_t)b * 32 + oc) * S3 + z * 1024 + y * 32 + ln;
                fout[o] = acc[j][r] + bias[oc] + fout[o];
            }
        }
    }
}

// ============ conv2: round-4/7 kb-split kernel — UNCHANGED =================
template <int IC, int OC, bool WRITE_H>
__global__ __launch_bounds__(512, 2) void conv_mfma_ks(
    const unsigned short* __restrict__ xin, const uint4* __restrict__ wTq,
    const float* __restrict__ bias, unsigned short* __restrict__ hout,
    float* __restrict__ fout)
{
    constexpr int ICB = IC / 32, WOC = OC / 32;
    constexpr int JT = (WOC == 2) ? 8 : 4;   // rows per wave (kb-split)
    constexpr int NW = ICB * 5;              // even
    constexpr int NIN = 2880;                // 20 rows * 36 x * 4 chunks
    constexpr int BUF = 20 * 36 * 80;        // 57600 B per buffer
    constexpr int PREI = 6;
    __shared__ __align__(16) char lds_in[2 * BUF];  // 115.2 KB

    const int tid = threadIdx.x;
    const int wave = tid >> 6, lane = tid & 63;
    const int ln = lane & 31, half = lane >> 5;
    const int kbw = wave & 1;                // K-half owned by this wave
    const int w2 = wave >> 1;                // pair id 0..3
    const int ochalf = (WOC == 2) ? (w2 >> 1) : 0;
    const int wy = (WOC == 2) ? (w2 & 1) : w2;
    const int z = blockIdx.x, ybl = blockIdx.y, b = blockIdx.z;
    const int y0 = ybl * 16;

    const uint4* wTl = wTq + half * 32 + ln;  // lane-fixed chunk offset

    // ---- window-invariant staging geometry (hoisted) ----
    int  goff[PREI];   // global offset sans (gz, icb) term
    bool act[PREI], yxok[PREI];
#pragma unroll
    for (int k = 0; k < PREI; ++k) {
        int i = tid + 512 * k;
        act[k] = i < NIN;
        int sub = i & 3, cc = i >> 2;
        int x36 = cc % 36, row = cc / 36;
        int gy = y0 - 2 + row, gx = x36 - 2;
        yxok[k] = ((unsigned)gy < 32u) & ((unsigned)gx < 32u);
        goff[k] = (b * 32768 + gy * 32 + gx) * IC + sub * 8;
    }

    f32x16 acc[JT];
#pragma unroll
    for (int j = 0; j < JT; ++j)
#pragma unroll
        for (int e = 0; e < 16; ++e) acc[j][e] = 0.f;

    uint4 prei[PREI];

    auto issue = [&](int icb, int dz) {
        int gz = z + dz - 2;
        bool zok = (unsigned)gz < 32u;
        int zoff = gz * (1024 * IC) + icb * 32;
#pragma unroll
        for (int k = 0; k < PREI; ++k) {
            if (act[k]) {
                uint4 v = {0u, 0u, 0u, 0u};
                if (zok & yxok[k])
                    v = *(const uint4*)(xin + goff[k] + zoff);
                prei[k] = v;
            }
        }
    };

    auto stage = [&](int buf) {
        char* base = lds_in + buf * BUF;
#pragma unroll
        for (int k = 0; k < PREI; ++k) {
            if (act[k]) {
                int i = tid + 512 * k;          // loff recomputed (VGPR diet)
                int sub = i & 3, cc = i >> 2;
                int row = cc / 36, x36 = cc - row * 36;
                *(uint4*)(base + row * 2880 + x36 * 80 + sub * 16) = prei[k];
            }
        }
    };

    bf16x8 bufA[5], bufB[5];

    // loads only this wave's kb half: 5 fragments (dy) per call
    auto fillA = [&](bool valid, int icb, int dz, int dx, bf16x8 (&buf)[5]) {
        if (!valid) return;
#pragma unroll
        for (int dy = 0; dy < 5; ++dy) {
            int tap = (dz * 5 + dy) * 5 + dx;
            int f = ((tap * ICB + icb) * WOC + ochalf) * 2 + kbw;
            buf[dy] = *(const bf16x8*)(wTl + (size_t)f * 64);
        }
    };

    // JT+4 ds_read_b128 feed 5*JT MFMAs (own kb only)
    auto compute = [&](const char* base, bf16x8 (&cur)[5], int dx) {
        bf16x8 brow[JT + 4];
#pragma unroll
        for (int r = 0; r < JT + 4; ++r)
            brow[r] = *(const bf16x8*)(base + (JT * wy + r) * 2880 +
                                       (ln + dx) * 80 + kbw * 32 + half * 16);
#pragma unroll
        for (int dy = 0; dy < 5; ++dy)
#pragma unroll
            for (int j = 0; j < JT; ++j)
                acc[j] = __builtin_amdgcn_mfma_f32_32x32x16_bf16(
                    cur[dy], brow[dy + j], acc[j], 0, 0, 0);
    };

    int cur = 0;
    auto window = [&](int w, bf16x8 (&X)[5], bf16x8 (&Y)[5]) {
        int icb = w / 5, dz = w - icb * 5;
        int nw = w + 1;
        int nicb = nw / 5, ndz = nw - nicb * 5;
        bool more = nw < NW;
        const char* rb = lds_in + cur * BUF;

        fillA(true, icb, dz, 1, Y);
        if (more) issue(nicb, ndz);         // next-window global loads
        compute(rb, X, 0);
        fillA(true, icb, dz, 2, X);
        compute(rb, Y, 1);
        fillA(true, icb, dz, 3, Y);
        if (more) stage(cur ^ 1);           // overlapped LDS write
        compute(rb, X, 2);
        fillA(true, icb, dz, 4, X);
        compute(rb, Y, 3);
        fillA(more, nicb, ndz, 0, Y);
        compute(rb, X, 4);
        // one barrier/window: drain only LDS ops; global loads stay in flight
        asm volatile("s_waitcnt lgkmcnt(0)\n\ts_barrier" ::: "memory");
        cur ^= 1;
    };

    // prologue: fill buf0, prefetch first A fragments
    issue(0, 0);
    fillA(true, 0, 0, 0, bufA);
    stage(0);
    __syncthreads();

    for (int wp = 0; wp < NW; wp += 2) {
        window(wp, bufA, bufB);
        window(wp + 1, bufB, bufA);
    }

    __syncthreads();
    // ---- cross-wave kb reduction: partner waves (wave^1) sum acc ----
    {
        char* red = lds_in;
#pragma unroll
        for (int rnd = 0; rnd < JT / 4; ++rnd) {
            if (kbw == 1) {
#pragma unroll
                for (int qi = 0; qi < 4; ++qi) {
                    const uint4* src = (const uint4*)&acc[rnd * 4 + qi];
#pragma unroll
                    for (int wd = 0; wd < 4; ++wd)
                        *(uint4*)(red + (w2 * 4 + qi) * 5120 + lane * 80 +
                                  wd * 16) = src[wd];
                }
            }
            __syncthreads();
            if (kbw == 0) {
#pragma unroll
                for (int qi = 0; qi < 4; ++qi) {
#pragma unroll
                    for (int wd = 0; wd < 4; ++wd) {
                        uint4 v = *(const uint4*)(red + (w2 * 4 + qi) * 5120 +
                                                  lane * 80 + wd * 16);
                        acc[rnd * 4 + qi][wd * 4 + 0] += __uint_as_float(v.x);
                        acc[rnd * 4 + qi][wd * 4 + 1] += __uint_as_float(v.y);
                        acc[rnd * 4 + qi][wd * 4 + 2] += __uint_as_float(v.z);
                        acc[rnd * 4 + qi][wd * 4 + 3] += __uint_as_float(v.w);
                    }
                }
            }
            __syncthreads();
        }
    }

    if (WRITE_H) {
#pragma unroll
        for (int j = 0; j < JT; ++j) {
            if (kbw == 0) {
                char* scr = lds_in + wy * (32 * 144);
#pragma unroll
                for (int r = 0; r < 16; ++r) {
                    int ocr = (r & 3) + 8 * (r >> 2) + 4 * half;
                    int oc = ochalf * 32 + ocr;
                    float v = acc[j][r] + bias[oc];
                    v = 0.5f * v * (1.f + erff(v * 0.70710678118654752f));
                    *(unsigned short*)(scr + ln * 144 + oc * 2) = f2bf(v);
                }
            }
            __syncthreads();
            {
                int u = tid;
                int wyi = u >> 8, rem = u & 255;
                int xx = rem >> 3, un = rem & 7;
                uint4 v = *(const uint4*)(lds_in + wyi * (32 * 144) +
                                          xx * 144 + un * 16);
                int y = y0 + 8 * wyi + j;
                *(uint4*)(hout + ((((size_t)b * 32 + z) * 32 + y) * 32 + xx)
                          * 64 + un * 8) = v;
            }
            __syncthreads();
        }
    } else {
        // final: bias + attention (already alpha-scaled in fout) added
        if (kbw == 0) {
#pragma unroll
            for (int j = 0; j < JT; ++j) {
                int y = y0 + JT * wy + j;
#pragma unroll
                for (int r = 0; r < 16; ++r) {
                    int oc = (r & 3) + 8 * (r >> 2) + 4 * half;
                    size_t o = ((size_t)b * 32 + oc) * S3 + z * 1024 + y * 32 + ln;
                    fout[o] = acc[j][r] + bias[oc] + fout[o];
                }
            }
        }
    }
}

// ---------------------------------------------------------------------------
extern "C" void kernel_launch(void* const* d_in, const int* in_sizes, int n_in,
                              void* d_out, int out_size, void* d_ws, size_t ws_size,
                              hipStream_t stream)
{
    const float* x       = (const float*)d_in[0];
    const float* basis   = (const float*)d_in[1];
    const float* mixer   = (const float*)d_in[2];
    const float* wq      = (const float*)d_in[3];
    const float* wk      = (const float*)d_in[4];
    const float* wv      = (const float*)d_in[5];
    const float* conv1_w = (const float*)d_in[6];
    const float* conv1_b = (const float*)d_in[7];
    const float* conv2_w = (const float*)d_in[8];
    const float* conv2_b = (const float*)d_in[9];
    const float* alpha   = (const float*)d_in[10];
    float* out = (float*)d_out;

    char* wsb = (char*)d_ws;
    unsigned short* xb  = (unsigned short*)wsb;               // 32 MiB
    unsigned short* h   = (unsigned short*)(wsb + 33554432);  // 16 MiB
    // token/qbuf alias h: both dead before conv1 writes h (same stream order)
    float* token = (float*)(wsb + 33554432);                  // 4 MiB
    float* qbuf  = (float*)(wsb + 37748736);                  // 4 MiB
    unsigned short* wT1 = (unsigned short*)(wsb + 50331648);  // 2 MiB
    unsigned short* wT2 = (unsigned short*)(wsb + 52379648);  // 0.5 MiB

    wt_transpose<128, 64><<<4000, 256, 0, stream>>>(conv1_w, wT1);
    wt_transpose<64, 32><<<1000, 256, 0, stream>>>(conv2_w, wT2);
    xb_transpose<<<dim3(1024, 4), 256, 0, stream>>>(x, xb);

    token_q_kernel<<<S3 / 256, 256, 0, stream>>>(basis, mixer, wq, token, qbuf);
    attention_kernel<<<2048, 256, 0, stream>>>(xb, token, qbuf, wk, wv, alpha,
                                               out);

    conv_mfma<128, 64, true><<<dim3(32, 2, 4), 512, 0, stream>>>(
        xb, (const uint4*)wT1, conv1_b, h, nullptr);
    conv_mfma_ks<64, 32, false><<<dim3(32, 2, 4), 512, 0, stream>>>(
        h, (const uint4*)wT2, conv2_b, nullptr, out);
}

// Round 10
// 447.881 us; speedup vs baseline: 2.1864x; 2.1864x over previous
//
#include <hip/hip_runtime.h>
#include <cstddef>
#include <cstdint>

#define S3 32768  // 32*32*32 spatial positions

typedef short bf16x8 __attribute__((ext_vector_type(8)));   // 8 bf16 in 4 VGPRs
typedef float f32x16 __attribute__((ext_vector_type(16)));

static __device__ inline unsigned short f2bf(float f) {
    unsigned int u = __float_as_uint(f);
    unsigned int r = (u + 0x7FFFu + ((u >> 16) & 1u)) >> 16;  // RNE
    return (unsigned short)r;
}

static __device__ inline float bf2f(unsigned short u) {
    return __uint_as_float(((unsigned)u) << 16);
}

// --------- weight transpose: wT[tap][icb][c][kb][chunk(=half*32+ln)][8ic] --
template <int IC, int OC>
__global__ __launch_bounds__(256) void wt_transpose(
    const float* __restrict__ w, unsigned short* __restrict__ wT)
{
    int t = blockIdx.x * 256 + threadIdx.x;  // < 125*IC*OC
    int e = t & 7;
    int chunk = (t >> 3) & 63;
    int kb = (t >> 9) & 1;
    int rest = t >> 10;                       // (tap*ICB + icb)*WOC + c
    int c = rest % (OC / 32); rest /= (OC / 32);
    int icb = rest % (IC / 32);
    int tap = rest / (IC / 32);
    int ln = chunk & 31, half = chunk >> 5;
    int oc = c * 32 + ln;
    int ic = icb * 32 + kb * 16 + half * 8 + e;
    wT[t] = f2bf(w[((size_t)oc * IC + ic) * 125 + tap]);
}

// ---------------- x transpose: xb[b][z][y][x][128 ic] bf16 -----------------
__global__ __launch_bounds__(256) void xb_transpose(
    const float* __restrict__ x, unsigned short* __restrict__ xb)
{
    __shared__ float tile[32][133];
    int zy = blockIdx.x, b = blockIdx.y;
    int t = threadIdx.x, xi = t & 31, ich = t >> 5;
#pragma unroll
    for (int k = 0; k < 16; ++k) {
        int ic = k * 8 + ich;
        tile[xi][ic] = x[(size_t)(b * 128 + ic) * S3 + zy * 32 + xi];
    }
    __syncthreads();
#pragma unroll
    for (int k = 0; k < 2; ++k) {
        int u = t + 256 * k;
        int xx = u >> 4, j = u & 15;
        __align__(16) unsigned short tmp[8];
#pragma unroll
        for (int e = 0; e < 8; ++e) tmp[e] = f2bf(tile[xx][j * 8 + e]);
        *(uint4*)(xb + ((size_t)b * S3 + zy * 32 + xx) * 128 + j * 8) =
            *(const uint4*)tmp;
    }
}

// --- token/q: qbuf fp32 [oc][s]; NEW: tokb bf16 [s][32c] (B-fragment-ready) -
__global__ __launch_bounds__(256) void token_q_kernel(
    const float* __restrict__ basis, const float* __restrict__ mixer,
    const float* __restrict__ wq, unsigned short* __restrict__ tokb,
    float* __restrict__ qbuf)
{
    int s = blockIdx.x * 256 + threadIdx.x;
    float tok[32];
#pragma unroll
    for (int c = 0; c < 32; ++c) tok[c] = 0.f;
#pragma unroll
    for (int r = 0; r < 8; ++r) {
        float bv = basis[r * S3 + s];
#pragma unroll
        for (int c = 0; c < 32; ++c) tok[c] += mixer[c * 8 + r] * bv;
    }
    __align__(16) unsigned short tb[32];
#pragma unroll
    for (int c = 0; c < 32; ++c) tb[c] = f2bf(tok[c]);
#pragma unroll
    for (int k = 0; k < 4; ++k)
        *(uint4*)(tokb + (size_t)s * 32 + k * 8) = *(const uint4*)(tb + k * 8);
    const float* wq4 = wq + 4 * 1024;
#pragma unroll
    for (int o = 0; o < 32; ++o) {
        float a = 0.f;
#pragma unroll
        for (int c = 0; c < 32; ++c) a += wq4[o * 32 + c] * tok[c];
        qbuf[o * S3 + s] = a;
    }
}

// ------------- attention via MFMA (NEW, replaces scalar attention) ---------
// All scalar variants (r6 fused 431us, r7 two-pass ~200us, r9 o-split 574us)
// are latency/issue-bound: 11K VALU-fma per position on 2 waves/SIMD. The
// math is 20 batched 32x32xS GEMMs + tiny pointwise -> MFMA.
// Fragment conventions reused from the PROVEN conv kernel:
//   A: lane(ln,half) holds W[oc=ln][c=kb*16+half*8+e]
//   B: lane(ln,half) holds X[c=kb*16+half*8+e][col=ln]
//   C: reg r -> row=(r&3)+8*(r>>2)+4*half, col=ln
// Per wave: one 32-position tile. K_j = mfma(Wk_j, Xfrag) (2 MFMAs);
// l_j = sum_r C[r]*q[r] (+shfl_xor 32); lane-local softmax (lane owns its
// column); PV: single accumulating C-tile over j with p_j folded into the
// B operand (per-column scale == per-lane scalar on 8 bf16). q from qbuf
// (coalesced); x from xb (contiguous 16B); token from tokb bf16 [s][32].
__global__ __launch_bounds__(256) void attention_mfma(
    const unsigned short* __restrict__ xb, const unsigned short* __restrict__ tokb,
    const float* __restrict__ qbuf, const float* __restrict__ wk,
    const float* __restrict__ wv, const float* __restrict__ alpha_p,
    float* __restrict__ out)
{
    const int wave = threadIdx.x >> 6, lane = threadIdx.x & 63;
    const int ln = lane & 31, half = lane >> 5;
    const int tl = blockIdx.x * 4 + wave;     // 4096 tiles
    const int g0 = tl * 32;
    const int b = g0 >> 15;
    const int s0 = g0 & (S3 - 1);

    // ---- A fragments: Wk/Wv, loaded once per wave (L2-hot, 20 KB each) ----
    bf16x8 ak[5][2], av[5][2];
#pragma unroll
    for (int j = 0; j < 5; ++j)
#pragma unroll
        for (int kb = 0; kb < 2; ++kb) {
            const float* ks = wk + ((j * 32 + ln) * 32 + kb * 16 + half * 8);
            const float* vs = wv + ((j * 32 + ln) * 32 + kb * 16 + half * 8);
            bf16x8 tk, tv;
#pragma unroll
            for (int e = 0; e < 8; ++e) {
                tk[e] = (short)f2bf(ks[e]);
                tv[e] = (short)f2bf(vs[e]);
            }
            ak[j][kb] = tk;
            av[j][kb] = tv;
        }

    // ---- q registers: q[row(r,half)][s0+ln], coalesced over lanes ----
    float qv[16];
#pragma unroll
    for (int r = 0; r < 16; ++r) {
        int row = (r & 3) + 8 * (r >> 2) + 4 * half;
        qv[r] = qbuf[(size_t)row * S3 + s0 + ln];
    }

    const unsigned short* xrow = xb + ((size_t)b * S3 + s0 + ln) * 128;
    const unsigned short* trow = tokb + (size_t)(s0 + ln) * 32;

    auto loadB = [&](int j, int kb) -> bf16x8 {
        if (j < 4)
            return *(const bf16x8*)(xrow + j * 32 + kb * 16 + half * 8);
        else
            return *(const bf16x8*)(trow + kb * 16 + half * 8);
    };

    // ---- QK^T pass ----
    const float scale = 0.17677669529663687f;
    float l[5];
#pragma unroll
    for (int j = 0; j < 5; ++j) {
        bf16x8 b0 = loadB(j, 0), b1 = loadB(j, 1);
        f32x16 c;
#pragma unroll
        for (int e = 0; e < 16; ++e) c[e] = 0.f;
        c = __builtin_amdgcn_mfma_f32_32x32x16_bf16(ak[j][0], b0, c, 0, 0, 0);
        c = __builtin_amdgcn_mfma_f32_32x32x16_bf16(ak[j][1], b1, c, 0, 0, 0);
        float part = 0.f;
#pragma unroll
        for (int r = 0; r < 16; ++r) part += c[r] * qv[r];
        part += __shfl_xor(part, 32);     // combine the two half rows
        l[j] = part * scale;
    }

    // ---- softmax (lane-local: each lane owns its column) ----
    float m = l[0];
#pragma unroll
    for (int j = 1; j < 5; ++j) m = fmaxf(m, l[j]);
    float p[5], sum = 0.f;
#pragma unroll
    for (int j = 0; j < 5; ++j) { p[j] = __expf(l[j] - m); sum += p[j]; }
    float inv = alpha_p[0] / sum;

    // ---- PV pass: p_j folded into B operand (per-lane = per-column) ----
    f32x16 ov;
#pragma unroll
    for (int e = 0; e < 16; ++e) ov[e] = 0.f;
#pragma unroll
    for (int j = 0; j < 5; ++j) {
        float pj = p[j];
#pragma unroll
        for (int kb = 0; kb < 2; ++kb) {
            bf16x8 bx = loadB(j, kb);
            bf16x8 pb;
#pragma unroll
            for (int e = 0; e < 8; ++e)
                pb[e] = (short)f2bf(bf2f((unsigned short)bx[e]) * pj);
            ov = __builtin_amdgcn_mfma_f32_32x32x16_bf16(av[j][kb], pb, ov,
                                                         0, 0, 0);
        }
    }

    // ---- write: out[(b*32+row)][s0+ln] (half-wave rows cover all 32 oc) ----
#pragma unroll
    for (int r = 0; r < 16; ++r) {
        int row = (r & 3) + 8 * (r >> 2) + 4 * half;
        out[((size_t)b * 32 + row) * S3 + s0 + ln] = ov[r] * inv;
    }
}

// ============ conv1: round-1 exact kernel (222.1 µs r1, 223.0 µs r7) =======
// 512-thread block (8 waves), 1 block/CU, block tile OC x (16y x 32x) x 1z.
// 2 oc-halves x 4 y-waves, JT=4. LDS input double-buffer, stage overlapped
// at gp==2, one raw lgkmcnt(0)+s_barrier per window. kb-split conv1
// ABANDONED (r4: spill; r8: diet still spilled + broke latency hiding).
template <int IC, int OC, bool WRITE_H>
__global__ __launch_bounds__(512, 2) void conv_mfma(
    const unsigned short* __restrict__ xin, const uint4* __restrict__ wTq,
    const float* __restrict__ bias, unsigned short* __restrict__ hout,
    float* __restrict__ fout)
{
    constexpr int ICB = IC / 32, WOC = OC / 32;
    constexpr int JT = 2 * WOC;        // 4 conv1
    constexpr int NW = ICB * 5;
    constexpr int NIN = 2880;          // 20 rows * 36 x * 4 chunks
    constexpr int BUF = 20 * 36 * 80;  // 57600 B per buffer
    __shared__ __align__(16) char lds_in[2 * BUF];  // 115.2 KB

    const int tid = threadIdx.x;
    const int wave = tid >> 6, lane = tid & 63;
    const int ln = lane & 31, half = lane >> 5;
    const int ochalf = (WOC == 2) ? (wave >> 2) : 0;
    const int wy = (WOC == 2) ? (wave & 3) : wave;
    const int z = blockIdx.x, ybl = blockIdx.y, b = blockIdx.z;
    const int y0 = ybl * 16;

    const uint4* wTl = wTq + half * 32 + ln;  // lane-fixed chunk offset

    // ---- window-invariant staging geometry (hoisted) ----
    int  goff[6];   // global offset sans (gz, icb) term
    int  loff[6];   // LDS byte offset within a buffer
    bool act[6], yxok[6];
#pragma unroll
    for (int k = 0; k < 6; ++k) {
        int i = tid + 512 * k;
        act[k] = i < NIN;
        int sub = i & 3, cc = i >> 2;
        int x36 = cc % 36, row = cc / 36;
        int gy = y0 - 2 + row, gx = x36 - 2;
        yxok[k] = ((unsigned)gy < 32u) & ((unsigned)gx < 32u);
        goff[k] = (b * 32768 + gy * 32 + gx) * IC + sub * 8;
        loff[k] = row * 2880 + x36 * 80 + sub * 16;
    }

    f32x16 acc[JT];
#pragma unroll
    for (int j = 0; j < JT; ++j)
#pragma unroll
        for (int e = 0; e < 16; ++e) acc[j][e] = 0.f;

    uint4 prei[6];

    auto issue = [&](int icb, int dz) {
        int gz = z + dz - 2;
        bool zok = (unsigned)gz < 32u;
        int zoff = gz * (1024 * IC) + icb * 32;
#pragma unroll
        for (int k = 0; k < 6; ++k) {
            if (act[k]) {
                uint4 v = {0u, 0u, 0u, 0u};
                if (zok & yxok[k])
                    v = *(const uint4*)(xin + goff[k] + zoff);
                prei[k] = v;
            }
        }
    };

    auto stage = [&](int buf) {
        char* base = lds_in + buf * BUF;
#pragma unroll
        for (int k = 0; k < 6; ++k)
            if (act[k]) *(uint4*)(base + loff[k]) = prei[k];
    };

    bf16x8 bufA[5], bufB[5];

    auto fillA = [&](bool valid, int icb, int dz, int dx, int kb,
                     bf16x8 (&buf)[5]) {
        if (!valid) return;
#pragma unroll
        for (int dy = 0; dy < 5; ++dy) {
            int tap = (dz * 5 + dy) * 5 + dx;
            int f = ((tap * ICB + icb) * WOC + ochalf) * 2 + kb;
            buf[dy] = *(const bf16x8*)(wTl + (size_t)f * 64);
        }
    };

    auto compute = [&](const char* base, bf16x8 (&cur)[5], int dx, int kb) {
        bf16x8 brow[JT + 4];
#pragma unroll
        for (int r = 0; r < JT + 4; ++r)
            brow[r] = *(const bf16x8*)(base + (JT * wy + r) * 2880 +
                                       (ln + dx) * 80 + kb * 32 + half * 16);
#pragma unroll
        for (int dy = 0; dy < 5; ++dy)
#pragma unroll
            for (int j = 0; j < JT; ++j)
                acc[j] = __builtin_amdgcn_mfma_f32_32x32x16_bf16(
                    cur[dy], brow[dy + j], acc[j], 0, 0, 0);
    };

    // prologue: fill buf0, prefetch first A fragments
    issue(0, 0);
    fillA(true, 0, 0, 0, 0, bufA);
    stage(0);
    __syncthreads();

    int cur = 0;
    for (int w = 0; w < NW; ++w) {
        int icb = w / 5, dz = w - icb * 5;
        int nw = w + 1;
        int nicb = nw / 5, ndz = nw - nicb * 5;
        bool more = nw < NW;
        const char* rb = lds_in + cur * BUF;

#pragma unroll
        for (int gp = 0; gp < 5; ++gp) {
            fillA(true, icb, dz, gp, 1, bufB);
            compute(rb, bufA, gp, 0);
            if (gp < 4) fillA(true, icb, dz, gp + 1, 0, bufA);
            else        fillA(more, nicb, ndz, 0, 0, bufA);
            if (gp == 0 && more) issue(nicb, ndz);          // next-window loads
            if (gp == 2 && more) stage(cur ^ 1);            // overlapped write
            compute(rb, bufB, gp, 1);
        }
        // one barrier/window: drain only LDS ops; global loads stay in flight
        asm volatile("s_waitcnt lgkmcnt(0)\n\ts_barrier" ::: "memory");
        cur ^= 1;
    }

    __syncthreads();
    if (WRITE_H) {
        // bias + exact GELU, transpose to [x][oc] via LDS scratch (4 y-waves
        // x 32 x x 64 oc rows), store h[b][z][y][x][64] bf16.
#pragma unroll
        for (int j = 0; j < JT; ++j) {
            char* scr = lds_in + wy * (32 * 144);
#pragma unroll
            for (int r = 0; r < 16; ++r) {
                int ocr = (r & 3) + 8 * (r >> 2) + 4 * half;
                int oc = ochalf * 32 + ocr;
                float v = acc[j][r] + bias[oc];
                v = 0.5f * v * (1.f + erff(v * 0.70710678118654752f));
                *(unsigned short*)(scr + ln * 144 + oc * 2) = f2bf(v);
            }
            __syncthreads();
#pragma unroll
            for (int k = 0; k < 2; ++k) {
                int u = tid + 512 * k;          // 1024 = 4 wy * 32 x * 8 un
                int wyi = u >> 8, rem = u & 255;
                int xx = rem >> 3, un = rem & 7;
                uint4 v = *(const uint4*)(lds_in + wyi * (32 * 144) +
                                          xx * 144 + un * 16);
                int y = y0 + 4 * wyi + j;
                *(uint4*)(hout + ((((size_t)b * 32 + z) * 32 + y) * 32 + xx)
                          * 64 + un * 8) = v;
            }
            __syncthreads();
        }
    } else {
        // final: bias + attention (already alpha-scaled in fout) added
#pragma unroll
        for (int j = 0; j < JT; ++j) {
            int y = y0 + JT * wy + j;
#pragma unroll
            for (int r = 0; r < 16; ++r) {
                int oc = (r & 3) + 8 * (r >> 2) + 4 * half;
                size_t o = ((size_t)b * 32 + oc) * S3 + z * 1024 + y * 32 + ln;
                fout[o] = acc[j][r] + bias[oc] + fout[o];
            }
        }
    }
}

// ============ conv2: round-4/7 kb-split kernel — UNCHANGED =================
template <int IC, int OC, bool WRITE_H>
__global__ __launch_bounds__(512, 2) void conv_mfma_ks(
    const unsigned short* __restrict__ xin, const uint4* __restrict__ wTq,
    const float* __restrict__ bias, unsigned short* __restrict__ hout,
    float* __restrict__ fout)
{
    constexpr int ICB = IC / 32, WOC = OC / 32;
    constexpr int JT = (WOC == 2) ? 8 : 4;   // rows per wave (kb-split)
    constexpr int NW = ICB * 5;              // even
    constexpr int NIN = 2880;                // 20 rows * 36 x * 4 chunks
    constexpr int BUF = 20 * 36 * 80;        // 57600 B per buffer
    constexpr int PREI = 6;
    __shared__ __align__(16) char lds_in[2 * BUF];  // 115.2 KB

    const int tid = threadIdx.x;
    const int wave = tid >> 6, lane = tid & 63;
    const int ln = lane & 31, half = lane >> 5;
    const int kbw = wave & 1;                // K-half owned by this wave
    const int w2 = wave >> 1;                // pair id 0..3
    const int ochalf = (WOC == 2) ? (w2 >> 1) : 0;
    const int wy = (WOC == 2) ? (w2 & 1) : w2;
    const int z = blockIdx.x, ybl = blockIdx.y, b = blockIdx.z;
    const int y0 = ybl * 16;

    const uint4* wTl = wTq + half * 32 + ln;  // lane-fixed chunk offset

    // ---- window-invariant staging geometry (hoisted) ----
    int  goff[PREI];   // global offset sans (gz, icb) term
    bool act[PREI], yxok[PREI];
#pragma unroll
    for (int k = 0; k < PREI; ++k) {
        int i = tid + 512 * k;
        act[k] = i < NIN;
        int sub = i & 3, cc = i >> 2;
        int x36 = cc % 36, row = cc / 36;
        int gy = y0 - 2 + row, gx = x36 - 2;
        yxok[k] = ((unsigned)gy < 32u) & ((unsigned)gx < 32u);
        goff[k] = (b * 32768 + gy * 32 + gx) * IC + sub * 8;
    }

    f32x16 acc[JT];
#pragma unroll
    for (int j = 0; j < JT; ++j)
#pragma unroll
        for (int e = 0; e < 16; ++e) acc[j][e] = 0.f;

    uint4 prei[PREI];

    auto issue = [&](int icb, int dz) {
        int gz = z + dz - 2;
        bool zok = (unsigned)gz < 32u;
        int zoff = gz * (1024 * IC) + icb * 32;
#pragma unroll
        for (int k = 0; k < PREI; ++k) {
            if (act[k]) {
                uint4 v = {0u, 0u, 0u, 0u};
                if (zok & yxok[k])
                    v = *(const uint4*)(xin + goff[k] + zoff);
                prei[k] = v;
            }
        }
    };

    auto stage = [&](int buf) {
        char* base = lds_in + buf * BUF;
#pragma unroll
        for (int k = 0; k < PREI; ++k) {
            if (act[k]) {
                int i = tid + 512 * k;          // loff recomputed (VGPR diet)
                int sub = i & 3, cc = i >> 2;
                int row = cc / 36, x36 = cc - row * 36;
                *(uint4*)(base + row * 2880 + x36 * 80 + sub * 16) = prei[k];
            }
        }
    };

    bf16x8 bufA[5], bufB[5];

    // loads only this wave's kb half: 5 fragments (dy) per call
    auto fillA = [&](bool valid, int icb, int dz, int dx, bf16x8 (&buf)[5]) {
        if (!valid) return;
#pragma unroll
        for (int dy = 0; dy < 5; ++dy) {
            int tap = (dz * 5 + dy) * 5 + dx;
            int f = ((tap * ICB + icb) * WOC + ochalf) * 2 + kbw;
            buf[dy] = *(const bf16x8*)(wTl + (size_t)f * 64);
        }
    };

    // JT+4 ds_read_b128 feed 5*JT MFMAs (own kb only)
    auto compute = [&](const char* base, bf16x8 (&cur)[5], int dx) {
        bf16x8 brow[JT + 4];
#pragma unroll
        for (int r = 0; r < JT + 4; ++r)
            brow[r] = *(const bf16x8*)(base + (JT * wy + r) * 2880 +
                                       (ln + dx) * 80 + kbw * 32 + half * 16);
#pragma unroll
        for (int dy = 0; dy < 5; ++dy)
#pragma unroll
            for (int j = 0; j < JT; ++j)
                acc[j] = __builtin_amdgcn_mfma_f32_32x32x16_bf16(
                    cur[dy], brow[dy + j], acc[j], 0, 0, 0);
    };

    int cur = 0;
    auto window = [&](int w, bf16x8 (&X)[5], bf16x8 (&Y)[5]) {
        int icb = w / 5, dz = w - icb * 5;
        int nw = w + 1;
        int nicb = nw / 5, ndz = nw - nicb * 5;
        bool more = nw < NW;
        const char* rb = lds_in + cur * BUF;

        fillA(true, icb, dz, 1, Y);
        if (more) issue(nicb, ndz);         // next-window global loads
        compute(rb, X, 0);
        fillA(true, icb, dz, 2, X);
        compute(rb, Y, 1);
        fillA(true, icb, dz, 3, Y);
        if (more) stage(cur ^ 1);           // overlapped LDS write
        compute(rb, X, 2);
        fillA(true, icb, dz, 4, X);
        compute(rb, Y, 3);
        fillA(more, nicb, ndz, 0, Y);
        compute(rb, X, 4);
        // one barrier/window: drain only LDS ops; global loads stay in flight
        asm volatile("s_waitcnt lgkmcnt(0)\n\ts_barrier" ::: "memory");
        cur ^= 1;
    };

    // prologue: fill buf0, prefetch first A fragments
    issue(0, 0);
    fillA(true, 0, 0, 0, bufA);
    stage(0);
    __syncthreads();

    for (int wp = 0; wp < NW; wp += 2) {
        window(wp, bufA, bufB);
        window(wp + 1, bufB, bufA);
    }

    __syncthreads();
    // ---- cross-wave kb reduction: partner waves (wave^1) sum acc ----
    {
        char* red = lds_in;
#pragma unroll
        for (int rnd = 0; rnd < JT / 4; ++rnd) {
            if (kbw == 1) {
#pragma unroll
                for (int qi = 0; qi < 4; ++qi) {
                    const uint4* src = (const uint4*)&acc[rnd * 4 + qi];
#pragma unroll
                    for (int wd = 0; wd < 4; ++wd)
                        *(uint4*)(red + (w2 * 4 + qi) * 5120 + lane * 80 +
                                  wd * 16) = src[wd];
                }
            }
            __syncthreads();
            if (kbw == 0) {
#pragma unroll
                for (int qi = 0; qi < 4; ++qi) {
#pragma unroll
                    for (int wd = 0; wd < 4; ++wd) {
                        uint4 v = *(const uint4*)(red + (w2 * 4 + qi) * 5120 +
                                                  lane * 80 + wd * 16);
                        acc[rnd * 4 + qi][wd * 4 + 0] += __uint_as_float(v.x);
                        acc[rnd * 4 + qi][wd * 4 + 1] += __uint_as_float(v.y);
                        acc[rnd * 4 + qi][wd * 4 + 2] += __uint_as_float(v.z);
                        acc[rnd * 4 + qi][wd * 4 + 3] += __uint_as_float(v.w);
                    }
                }
            }
            __syncthreads();
        }
    }

    if (WRITE_H) {
#pragma unroll
        for (int j = 0; j < JT; ++j) {
            if (kbw == 0) {
                char* scr = lds_in + wy * (32 * 144);
#pragma unroll
                for (int r = 0; r < 16; ++r) {
                    int ocr = (r & 3) + 8 * (r >> 2) + 4 * half;
                    int oc = ochalf * 32 + ocr;
                    float v = acc[j][r] + bias[oc];
                    v = 0.5f * v * (1.f + erff(v * 0.70710678118654752f));
                    *(unsigned short*)(scr + ln * 144 + oc * 2) = f2bf(v);
                }
            }
            __syncthreads();
            {
                int u = tid;
                int wyi = u >> 8, rem = u & 255;
                int xx = rem >> 3, un = rem & 7;
                uint4 v = *(const uint4*)(lds_in + wyi * (32 * 144) +
                                          xx * 144 + un * 16);
                int y = y0 + 8 * wyi + j;
                *(uint4*)(hout + ((((size_t)b * 32 + z) * 32 + y) * 32 + xx)
                          * 64 + un * 8) = v;
            }
            __syncthreads();
        }
    } else {
        // final: bias + attention (already alpha-scaled in fout) added
        if (kbw == 0) {
#pragma unroll
            for (int j = 0; j < JT; ++j) {
                int y = y0 + JT * wy + j;
#pragma unroll
                for (int r = 0; r < 16; ++r) {
                    int oc = (r & 3) + 8 * (r >> 2) + 4 * half;
                    size_t o = ((size_t)b * 32 + oc) * S3 + z * 1024 + y * 32 + ln;
                    fout[o] = acc[j][r] + bias[oc] + fout[o];
                }
            }
        }
    }
}

// ---------------------------------------------------------------------------
extern "C" void kernel_launch(void* const* d_in, const int* in_sizes, int n_in,
                              void* d_out, int out_size, void* d_ws, size_t ws_size,
                              hipStream_t stream)
{
    const float* x       = (const float*)d_in[0];
    const float* basis   = (const float*)d_in[1];
    const float* mixer   = (const float*)d_in[2];
    const float* wq      = (const float*)d_in[3];
    const float* wk      = (const float*)d_in[4];
    const float* wv      = (const float*)d_in[5];
    const float* conv1_w = (const float*)d_in[6];
    const float* conv1_b = (const float*)d_in[7];
    const float* conv2_w = (const float*)d_in[8];
    const float* conv2_b = (const float*)d_in[9];
    const float* alpha   = (const float*)d_in[10];
    float* out = (float*)d_out;

    char* wsb = (char*)d_ws;
    unsigned short* xb   = (unsigned short*)wsb;               // 32 MiB
    unsigned short* h    = (unsigned short*)(wsb + 33554432);  // 16 MiB
    // tokb/qbuf alias h: both dead before conv1 writes h (same stream order)
    unsigned short* tokb = (unsigned short*)(wsb + 33554432);  // 2 MiB
    float* qbuf          = (float*)(wsb + 37748736);           // 4 MiB
    unsigned short* wT1  = (unsigned short*)(wsb + 50331648);  // 2 MiB
    unsigned short* wT2  = (unsigned short*)(wsb + 52379648);  // 0.5 MiB

    wt_transpose<128, 64><<<4000, 256, 0, stream>>>(conv1_w, wT1);
    wt_transpose<64, 32><<<1000, 256, 0, stream>>>(conv2_w, wT2);
    xb_transpose<<<dim3(1024, 4), 256, 0, stream>>>(x, xb);

    token_q_kernel<<<S3 / 256, 256, 0, stream>>>(basis, mixer, wq, tokb, qbuf);
    attention_mfma<<<1024, 256, 0, stream>>>(xb, tokb, qbuf, wk, wv, alpha,
                                             out);

    conv_mfma<128, 64, true><<<dim3(32, 2, 4), 512, 0, stream>>>(
        xb, (const uint4*)wT1, conv1_b, h, nullptr);
    conv_mfma_ks<64, 32, false><<<dim3(32, 2, 4), 512, 0, stream>>>(
        h, (const uint4*)wT2, conv2_b, nullptr, out);
}